// Round 7
// baseline (649.384 us; speedup 1.0000x reference)
//
#include <hip/hip_runtime.h>
#include <hip/hip_bf16.h>
#include <cstdint>
#include <cstddef>

typedef __hip_bfloat16 bf16;
typedef __bf16 bf16x8 __attribute__((ext_vector_type(8)));
typedef float f32x4 __attribute__((ext_vector_type(4)));

#define BB 2
#define TT 1024
#define CC 1024
#define HH 16

__device__ __forceinline__ bf16 f2b(float v){ return __float2bfloat16(v); }

// quad (4-lane) sum via DPP quad_perm — VALU latency, no DS pipe
__device__ __forceinline__ float quad_add(float x) {
    x += __int_as_float(__builtin_amdgcn_mov_dpp(__float_as_int(x), 0xB1, 0xF, 0xF, true)); // xor 1
    x += __int_as_float(__builtin_amdgcn_mov_dpp(__float_as_int(x), 0x4E, 0xF, 0xF, true)); // xor 2
    return x;
}

// ---------------- batched transpose+convert: f32 [R][S] -> bf16 [S][R] ----------------
struct TrDesc { const float* in; bf16* out; int R, S; };
struct TrArgs { TrDesc d[12]; };

__global__ __launch_bounds__(256) void transpose_batch(TrArgs args)
{
    TrDesc t = args.d[blockIdx.z];
    __shared__ float tile[32][33];
    int s0 = blockIdx.x * 32, r0 = blockIdx.y * 32;
    if (s0 >= t.S || r0 >= t.R) return;      // block-uniform early exit
    int tx = threadIdx.x & 31, ty = threadIdx.x >> 5;
#pragma unroll
    for (int i = 0; i < 4; i++) {
        int r = r0 + ty + i * 8, s = s0 + tx;
        if (r < t.R && s < t.S) tile[ty + i * 8][tx] = t.in[(size_t)r * t.S + s];
    }
    __syncthreads();
#pragma unroll
    for (int i = 0; i < 4; i++) {
        int s = s0 + ty + i * 8, r = r0 + tx;
        if (s < t.S && r < t.R) t.out[(size_t)s * t.R + r] = f2b(tile[tx][ty + i * 8]);
    }
}

// ---------------- token-shift mix (f32 in -> bf16 out) + v_first passthrough ----------------
__global__ __launch_bounds__(256) void mix_kernel(
    const float* __restrict__ x, const float* __restrict__ vfirst,
    const float* __restrict__ mr, const float* __restrict__ mw, const float* __restrict__ mk,
    const float* __restrict__ mv, const float* __restrict__ ma, const float* __restrict__ mg,
    bf16* __restrict__ xr, bf16* __restrict__ xw, bf16* __restrict__ xk,
    bf16* __restrict__ xv, bf16* __restrict__ xa, bf16* __restrict__ xg,
    float* __restrict__ vout)
{
    int row = blockIdx.x;
    int t = row & (TT - 1);
    size_t base = (size_t)row * CC;
    for (int c = threadIdx.x; c < CC; c += 256) {
        float xc = x[base + c];
        float xp = (t > 0) ? x[base - CC + c] : 0.f;
        float d = xp - xc;
        xr[base + c] = f2b(xc + d * mr[c]);
        xw[base + c] = f2b(xc + d * mw[c]);
        xk[base + c] = f2b(xc + d * mk[c]);
        xv[base + c] = f2b(xc + d * mv[c]);
        xa[base + c] = f2b(xc + d * ma[c]);
        xg[base + c] = f2b(xc + d * mg[c]);
        vout[base + c] = vfirst[base + c];   // exact f32 passthrough
    }
}

// ---------------- shared MFMA tile body: 128x128 tile of A[M,K] @ BT[N,K]^T ----------------
template <class EmitF>
__device__ __forceinline__ void gemm_tile(const bf16* __restrict__ A, const bf16* __restrict__ BT,
                                          int K, int m0, int n0, EmitF emit)
{
    __shared__ __align__(16) bf16 Atile[128 * 32];
    __shared__ __align__(16) bf16 Btile[128 * 32];
    int tid = threadIdx.x;
    int w = tid >> 6, lane = tid & 63;
    int wr = w >> 1, wc = w & 1;
    int quad = lane >> 4, l16 = lane & 15;

    f32x4 zero = {0.f, 0.f, 0.f, 0.f};
    f32x4 acc[4][4];
#pragma unroll
    for (int i = 0; i < 4; i++)
#pragma unroll
        for (int j = 0; j < 4; j++) acc[i][j] = zero;

    int rr = lane >> 2;            // 0..15
    int cs = lane & 3;             // chunk slot in LDS
    int ra0 = w * 32 + rr;         // rows this lane stages
    int ra1 = ra0 + 16;
    int cg0 = cs ^ ((ra0 >> 1) & 3);   // global chunk (XOR swizzle)
    int cg1 = cs ^ ((ra1 >> 1) & 3);

    for (int k0 = 0; k0 < K; k0 += 32) {
        uint4 av0 = *reinterpret_cast<const uint4*>(A  + (size_t)(m0 + ra0) * K + k0 + cg0 * 8);
        uint4 av1 = *reinterpret_cast<const uint4*>(A  + (size_t)(m0 + ra1) * K + k0 + cg1 * 8);
        uint4 bv0 = *reinterpret_cast<const uint4*>(BT + (size_t)(n0 + ra0) * K + k0 + cg0 * 8);
        uint4 bv1 = *reinterpret_cast<const uint4*>(BT + (size_t)(n0 + ra1) * K + k0 + cg1 * 8);
        __syncthreads();           // previous tile's reads complete
        *reinterpret_cast<uint4*>(&Atile[ra0 * 32 + cs * 8]) = av0;
        *reinterpret_cast<uint4*>(&Atile[ra1 * 32 + cs * 8]) = av1;
        *reinterpret_cast<uint4*>(&Btile[ra0 * 32 + cs * 8]) = bv0;
        *reinterpret_cast<uint4*>(&Btile[ra1 * 32 + cs * 8]) = bv1;
        __syncthreads();           // staging visible

        bf16x8 af[4], bfr[4];
#pragma unroll
        for (int mi = 0; mi < 4; mi++) {
            int m = wr * 64 + mi * 16 + l16;
            int c2 = quad ^ ((m >> 1) & 3);
            af[mi] = *reinterpret_cast<const bf16x8*>(&Atile[m * 32 + c2 * 8]);
        }
#pragma unroll
        for (int ni = 0; ni < 4; ni++) {
            int n = wc * 64 + ni * 16 + l16;
            int c2 = quad ^ ((n >> 1) & 3);
            bfr[ni] = *reinterpret_cast<const bf16x8*>(&Btile[n * 32 + c2 * 8]);
        }
#pragma unroll
        for (int mi = 0; mi < 4; mi++)
#pragma unroll
            for (int ni = 0; ni < 4; ni++)
                acc[mi][ni] = __builtin_amdgcn_mfma_f32_16x16x32_bf16(af[mi], bfr[ni], acc[mi][ni], 0, 0, 0);
    }

#pragma unroll
    for (int mi = 0; mi < 4; mi++)
#pragma unroll
        for (int ni = 0; ni < 4; ni++)
#pragma unroll
            for (int rg = 0; rg < 4; rg++) {
                int m = m0 + wr * 64 + mi * 16 + quad * 4 + rg;
                int n = n0 + wc * 64 + ni * 16 + l16;
                emit(m, n, acc[mi][ni][rg]);
            }
}

// ---------------- big projections r/k/v: z-batched, N=K=1024, f32 out ----------------
struct B3Args { const bf16* A[3]; const bf16* BT[3]; float* out[3]; };
__global__ __launch_bounds__(256) void big3_kernel(B3Args args)
{
    int z = blockIdx.z;
    float* out = args.out[z];
    gemm_tile(args.A[z], args.BT[z], 1024, blockIdx.x * 128, blockIdx.y * 128,
              [&](int m, int n, float v) { out[(size_t)m * 1024 + n] = v; });
}

// ---------------- lora stage 1: z-batched (different A per z), small N, bf16 out ----------------
struct L1Desc { const bf16* A; const bf16* BT; bf16* outB; int N; int mode; }; // mode: 0 plain, 2 tanh, 3 sigmoid
struct L1Args { L1Desc d[4]; };
__global__ __launch_bounds__(256) void lora1_kernel(L1Args args)
{
    L1Desc dz = args.d[blockIdx.z];
    gemm_tile(dz.A, dz.BT, 1024, blockIdx.x * 128, 0,
              [&](int m, int n, float v) {
                  if (n < dz.N) {
                      float r = (dz.mode == 2) ? tanhf(v)
                              : (dz.mode == 3) ? 1.f / (1.f + expf(-v)) : v;
                      dz.outB[(size_t)m * dz.N + n] = f2b(r);
                  }
              });
}

// ---------------- lora stage 2 (+g2): z-batched, N=1024, f32 out, fused epilogues ----------------
struct L2Desc { const bf16* A; const bf16* BT; const float* bias; float* outF; int K; int mode; };
struct L2Args { L2Desc d[4]; const float* vraw; const float* vfirst; };
__global__ __launch_bounds__(256) void lora2_kernel(L2Args args)
{
    L2Desc dz = args.d[blockIdx.z];
    gemm_tile(dz.A, dz.BT, dz.K, blockIdx.x * 128, blockIdx.y * 128,
              [&](int m, int n, float v) {
                  size_t idx = (size_t)m * 1024 + n;
                  if (dz.mode == 4) {
                      float xx = v + dz.bias[n];
                      float ww = -log1pf(expf(-xx)) - 0.5f;   // -softplus(-x) - 0.5
                      dz.outF[idx] = expf(-expf(ww));
                  } else if (dz.mode == 5) {
                      float xx = v + dz.bias[n];
                      dz.outF[idx] = 1.f / (1.f + expf(-xx));
                  } else if (dz.mode == 6) {
                      float gate = 1.f / (1.f + expf(-(v + dz.bias[n])));
                      float vr = args.vraw[idx];
                      dz.outF[idx] = vr + (args.vfirst[idx] - vr) * gate;
                  } else {
                      dz.outF[idx] = v;
                  }
              });
}

// ---------------- final output projection ----------------
__global__ __launch_bounds__(256) void final_kernel(const bf16* __restrict__ A, const bf16* __restrict__ BT,
                                                    float* __restrict__ out)
{
    gemm_tile(A, BT, 1024, blockIdx.x * 128, blockIdx.y * 128,
              [&](int m, int n, float v) { out[(size_t)m * 1024 + n] = v; });
}

// ---------------- pack: kk norm, k scale -> planar PK stream + BC; k write-back ----------------
// PK[bh][t][0..63]=k_scaled, [64..127]=kk, [128..191]=bb ; BC[bh*TT+t]={Σ bb·r, Σ k·r}
__global__ __launch_bounds__(256) void pack_kernel(
    float* __restrict__ k, const float* __restrict__ a, const float* __restrict__ r,
    const float* __restrict__ kkw, const float* __restrict__ kaw,
    float* __restrict__ PK, float2* __restrict__ BC)
{
    int tid = threadIdx.x;
    int wave = tid >> 6, lane = tid & 63;
    int idx = blockIdx.x * 4 + wave;        // (b*TT+t)*HH + h
    size_t off = (size_t)idx * 64 + lane;
    int c = (idx & 15) * 64 + lane;
    float kraw = k[off];
    float av = a[off];
    float kkv = kraw * kkw[c];
    float s = kkv * kkv;
#pragma unroll
    for (int m = 32; m; m >>= 1) s += __shfl_xor(s, m);
    float kkn = kkv / fmaxf(sqrtf(s), 1e-12f);
    float ks = kraw * (1.f + (av - 1.f) * kaw[c]);
    k[off] = ks;                            // write-back for gn_kernel
    float bb = kkn * av;
    float rv = r[off];
    float bt = bb * rv, ct = ks * rv;
#pragma unroll
    for (int m = 32; m; m >>= 1) { bt += __shfl_xor(bt, m); ct += __shfl_xor(ct, m); }
    int b = idx >> 14;                      // / (TT*HH)
    int h = idx & 15;
    int t = (idx >> 4) & (TT - 1);
    size_t sidx = (size_t)(b * HH + h) * TT + t;
    float* pw = PK + sidx * 192;
    pw[lane] = ks; pw[64 + lane] = kkn; pw[128 + lane] = bb;
    if (lane == 0) BC[sidx] = make_float2(bt, ct);
}

// ---------------- sequential state recurrence (register-direct, no LDS) ----------------
// 1 wave/block; wave owns rows [wq*16, wq*16+16). Lane (i=lane>>2, q=lane&3) owns S[row][16q..16q+16).
// Per step per lane: 20 global dwordx4 (planar slices) + v dword + bc; depth-2 ping-pong prefetch.
struct Step {
    f32x4 q4[4], d4[4], r4[4], k4[4], b4[4];
    float vi, bt, ct;
};

__device__ __forceinline__ void load_step(Step& s, const float* __restrict__ pk,
                                          const float* __restrict__ pr, const float* __restrict__ pd,
                                          const float* __restrict__ pv, const float2* __restrict__ pbc,
                                          int t, int jb)
{
    const float* kb = pk + (size_t)t * 192;
    const float* rr = pr + (size_t)t * CC + jb;
    const float* dd = pd + (size_t)t * CC + jb;
    // order: earliest-needed first (kk heads the sa chain, then d/r for od, then k/bb/v/bc)
#pragma unroll
    for (int m = 0; m < 4; m++) s.q4[m] = *(const f32x4*)(kb + 64 + jb + 4 * m);
#pragma unroll
    for (int m = 0; m < 4; m++) s.d4[m] = *(const f32x4*)(dd + 4 * m);
#pragma unroll
    for (int m = 0; m < 4; m++) s.r4[m] = *(const f32x4*)(rr + 4 * m);
#pragma unroll
    for (int m = 0; m < 4; m++) s.k4[m] = *(const f32x4*)(kb + jb + 4 * m);
#pragma unroll
    for (int m = 0; m < 4; m++) s.b4[m] = *(const f32x4*)(kb + 128 + jb + 4 * m);
    s.vi = pv[(size_t)t * CC];
    float2 bc = pbc[t];
    s.bt = bc.x; s.ct = bc.y;
}

__device__ __forceinline__ float step_update(const Step& sd, float S[16])
{
    float s0 = 0, s1 = 0, s2 = 0, s3 = 0;
    float o0 = 0, o1 = 0, o2 = 0, o3 = 0;
#pragma unroll
    for (int m = 0; m < 4; m++) {
        s0 = fmaf(S[4 * m + 0], sd.q4[m][0], s0);
        s1 = fmaf(S[4 * m + 1], sd.q4[m][1], s1);
        s2 = fmaf(S[4 * m + 2], sd.q4[m][2], s2);
        s3 = fmaf(S[4 * m + 3], sd.q4[m][3], s3);
        o0 = fmaf(S[4 * m + 0] * sd.d4[m][0], sd.r4[m][0], o0);
        o1 = fmaf(S[4 * m + 1] * sd.d4[m][1], sd.r4[m][1], o1);
        o2 = fmaf(S[4 * m + 2] * sd.d4[m][2], sd.r4[m][2], o2);
        o3 = fmaf(S[4 * m + 3] * sd.d4[m][3], sd.r4[m][3], o3);
    }
    float sa = -((s0 + s1) + (s2 + s3));
    sa = quad_add(sa);                    // full-row sa (all 4 lanes)
    float od = quad_add((o0 + o1) + (o2 + o3));
    float o = fmaf(sd.vi, sd.ct, fmaf(sa, sd.bt, od));
#pragma unroll
    for (int m = 0; m < 16; m++) {
        int mm = m >> 2, e = m & 3;
        S[m] = fmaf(sd.vi, sd.k4[mm][e], fmaf(sa, sd.b4[mm][e], S[m] * sd.d4[mm][e]));
    }
    return o;
}

__global__ __launch_bounds__(64, 1) void scan_kernel(
    const float* __restrict__ PK, const float* __restrict__ rbuf,
    const float* __restrict__ dbuf, const float* __restrict__ vbuf,
    const float2* __restrict__ BC, float* __restrict__ ybuf)
{
    const int lane = threadIdx.x;
    const int bh = blockIdx.x >> 2;
    const int b = bh >> 4, h = bh & 15;
    const int wq = blockIdx.x & 3;
    const int row = wq * 16 + (lane >> 2);
    const int q = lane & 3, jb = q * 16;

    float S[16];
#pragma unroll
    for (int m = 0; m < 16; m++) S[m] = 0.f;

    const float* pk = PK + (size_t)bh * TT * 192;
    const float* pr = rbuf + (size_t)b * TT * CC + h * 64;
    const float* pd = dbuf + (size_t)b * TT * CC + h * 64;
    const float* pv = vbuf + (size_t)b * TT * CC + h * 64 + row;
    const float2* pbc = BC + (size_t)bh * TT;

    Step A, Bs;
    load_step(A, pk, pr, pd, pv, pbc, 0, jb);
    load_step(Bs, pk, pr, pd, pv, pbc, 1, jb);

    float* py = ybuf + (size_t)b * TT * CC + h * 64 + row;

    for (int t = 0; t < TT; t += 2) {
        float o = step_update(A, S);
        if (q == 0) *py = o;
        int t2 = (t + 2 < TT) ? t + 2 : TT - 1;
        load_step(A, pk, pr, pd, pv, pbc, t2, jb);

        o = step_update(Bs, S);
        if (q == 0) py[CC] = o;
        int t3 = (t + 3 < TT) ? t + 3 : TT - 1;
        load_step(Bs, pk, pr, pd, pv, pbc, t3, jb);

        py += 2 * CC;
    }
}

// ---------------- groupnorm + residual + gate -> z (bf16), 4 heads/block ----------------
__global__ __launch_bounds__(256) void gn_kernel(
    const float* __restrict__ y, const float* __restrict__ r, const float* __restrict__ k,
    const float* __restrict__ v, const float* __restrict__ g,
    const float* __restrict__ lnw, const float* __restrict__ lnb,
    const float* __restrict__ rk, bf16* __restrict__ z)
{
    int tid = threadIdx.x;
    int idx = blockIdx.x * 4 + (tid >> 6);   // (b*T+t)*16 + h
    int lane = tid & 63;
    size_t off = (size_t)idx * 64 + lane;
    int c = (idx & 15) * 64 + lane;
    float yv = y[off];
    float rv = r[off], kv = k[off], vv = v[off];
    float s1 = yv, s2 = yv * yv, s3 = rv * kv * rk[c];
#pragma unroll
    for (int m = 32; m; m >>= 1) {
        s1 += __shfl_xor(s1, m);
        s2 += __shfl_xor(s2, m);
        s3 += __shfl_xor(s3, m);
    }
    float mu = s1 * (1.f / 64.f);
    float var = fmaxf(s2 * (1.f / 64.f) - mu * mu, 0.f);
    float yn = (yv - mu) * rsqrtf(var + 64e-5f) * lnw[c] + lnb[c];
    float out = (yn + s3 * vv) * g[off];
    z[off] = f2b(out);
}

// ---------------- host ----------------
extern "C" void kernel_launch(void* const* d_in, const int* in_sizes, int n_in,
                              void* d_out, int out_size, void* d_ws, size_t ws_size,
                              hipStream_t stream)
{
    const float* x       = (const float*)d_in[0];
    const float* v_first = (const float*)d_in[1];
    const float* x_r = (const float*)d_in[2];
    const float* x_w = (const float*)d_in[3];
    const float* x_k = (const float*)d_in[4];
    const float* x_v = (const float*)d_in[5];
    const float* x_a = (const float*)d_in[6];
    const float* x_g = (const float*)d_in[7];
    const float* w1 = (const float*)d_in[8];
    const float* w2 = (const float*)d_in[9];
    const float* w0 = (const float*)d_in[10];
    const float* a1 = (const float*)d_in[11];
    const float* a2 = (const float*)d_in[12];
    const float* a0 = (const float*)d_in[13];
    const float* v1 = (const float*)d_in[14];
    const float* v2 = (const float*)d_in[15];
    const float* v0 = (const float*)d_in[16];
    const float* g1 = (const float*)d_in[17];
    const float* g2 = (const float*)d_in[18];
    const float* k_k = (const float*)d_in[19];
    const float* k_a = (const float*)d_in[20];
    const float* r_k = (const float*)d_in[21];
    const float* W_r = (const float*)d_in[22];
    const float* W_k = (const float*)d_in[23];
    const float* W_v = (const float*)d_in[24];
    const float* W_o = (const float*)d_in[25];
    const float* ln_w = (const float*)d_in[26];
    const float* ln_b = (const float*)d_in[27];

    const size_t BTC = (size_t)BB * TT * CC;   // 2M
    const int M = BB * TT;                     // 2048

    char* ws = (char*)d_ws;
    size_t off = 0;
    auto alloc = [&](size_t bytes) -> char* {
        char* p = ws + off;
        off += (bytes + 255) & ~(size_t)255;
        return p;
    };

    // ---- region0: everything here is dead before pack_kernel; PK aliases it ----
    bf16* xr = (bf16*)alloc(BTC * 2);
    bf16* xw = (bf16*)alloc(BTC * 2);
    bf16* xk = (bf16*)alloc(BTC * 2);
    bf16* xv = (bf16*)alloc(BTC * 2);
    bf16* xa = (bf16*)alloc(BTC * 2);
    bf16* xg = (bf16*)alloc(BTC * 2);
    bf16* WrT = (bf16*)alloc(1024 * 1024 * 2);
    bf16* WkT = (bf16*)alloc(1024 * 1024 * 2);
    bf16* WvT = (bf16*)alloc(1024 * 1024 * 2);
    bf16* w1T = (bf16*)alloc(128 * 1024 * 2);   // 64 rows used, pad benign
    bf16* a1T = (bf16*)alloc(128 * 1024 * 2);
    bf16* v1T = (bf16*)alloc(128 * 1024 * 2);   // 32 rows used
    bf16* g1T = (bf16*)alloc(128 * 1024 * 2);
    bf16* w2T = (bf16*)alloc(1024 * 64 * 2);
    bf16* a2T = (bf16*)alloc(1024 * 64 * 2);
    bf16* v2T = (bf16*)alloc(1024 * 32 * 2);
    bf16* g2T = (bf16*)alloc(1024 * 128 * 2);
    bf16* h_w = (bf16*)alloc((size_t)M * 64 * 2);
    bf16* h_a = (bf16*)alloc((size_t)M * 64 * 2);
    bf16* h_v = (bf16*)alloc((size_t)M * 32 * 2);
    bf16* h_g = (bf16*)alloc((size_t)M * 128 * 2);

    // PK aliases region0 (24 MB); continue past max(region0, PK)
    float* PK = (float*)ws;
    size_t pk_end = (size_t)BB * HH * TT * 192 * 4;   // 25,165,824
    if (off < pk_end) off = pk_end;
    off = (off + 255) & ~(size_t)255;

    // ---- live across pack/scan ----
    bf16* WoT = (bf16*)alloc(1024 * 1024 * 2);
    float2* BC = (float2*)alloc((size_t)BB * HH * TT * 8);
    float* rbuf = (float*)alloc(BTC * 4);
    float* kbuf = (float*)alloc(BTC * 4);
    float* vraw = (float*)alloc(BTC * 4);   // reused as ybuf after lora2
    float* vbuf = (float*)alloc(BTC * 4);
    float* dbuf = (float*)alloc(BTC * 4);   // reused as zbuf (bf16) after scan
    float* abuf = (float*)alloc(BTC * 4);
    float* gbuf = (float*)alloc(BTC * 4);

    float* ybuf = vraw;
    bf16*  zbuf = (bf16*)dbuf;

    (void)in_sizes; (void)n_in; (void)out_size; (void)ws_size;

    // 1) all weight transposes in one launch
    TrArgs ta;
    ta.d[0]  = {W_r, WrT, 1024, 1024};
    ta.d[1]  = {W_k, WkT, 1024, 1024};
    ta.d[2]  = {W_v, WvT, 1024, 1024};
    ta.d[3]  = {W_o, WoT, 1024, 1024};
    ta.d[4]  = {w1, w1T, 1024, 64};
    ta.d[5]  = {a1, a1T, 1024, 64};
    ta.d[6]  = {v1, v1T, 1024, 32};
    ta.d[7]  = {g1, g1T, 1024, 128};
    ta.d[8]  = {w2, w2T, 64, 1024};
    ta.d[9]  = {a2, a2T, 64, 1024};
    ta.d[10] = {v2, v2T, 32, 1024};
    ta.d[11] = {g2, g2T, 128, 1024};
    transpose_batch<<<dim3(32, 32, 12), 256, 0, stream>>>(ta);

    // 2) token-shift mix (+ v_first passthrough)
    float* vout = (float*)d_out + BTC;
    mix_kernel<<<BB * TT, 256, 0, stream>>>(x, v_first, x_r, x_w, x_k, x_v, x_a, x_g,
                                            xr, xw, xk, xv, xa, xg, vout);

    // 3) big projections r/k/v
    B3Args b3;
    b3.A[0] = xr; b3.A[1] = xk; b3.A[2] = xv;
    b3.BT[0] = WrT; b3.BT[1] = WkT; b3.BT[2] = WvT;
    b3.out[0] = rbuf; b3.out[1] = kbuf; b3.out[2] = vraw;
    big3_kernel<<<dim3(16, 8, 3), 256, 0, stream>>>(b3);

    // 4) lora stage 1
    L1Args l1;
    l1.d[0] = {xw, w1T, h_w, 64, 2};
    l1.d[1] = {xa, a1T, h_a, 64, 0};
    l1.d[2] = {xv, v1T, h_v, 32, 0};
    l1.d[3] = {xg, g1T, h_g, 128, 3};
    lora1_kernel<<<dim3(16, 1, 4), 256, 0, stream>>>(l1);

    // 5) lora stage 2 + g2
    L2Args l2;
    l2.d[0] = {h_w, w2T, w0, dbuf, 64, 4};
    l2.d[1] = {h_a, a2T, a0, abuf, 64, 5};
    l2.d[2] = {h_v, v2T, v0, vbuf, 32, 6};
    l2.d[3] = {h_g, g2T, nullptr, gbuf, 128, 0};
    l2.vraw = vraw; l2.vfirst = v_first;
    lora2_kernel<<<dim3(16, 8, 4), 256, 0, stream>>>(l2);

    // 6) pack (planar PK + BC; writes scaled k back to kbuf)
    pack_kernel<<<BB * TT * HH / 4, 256, 0, stream>>>(kbuf, abuf, rbuf, k_k, k_a, PK, BC);

    // 7) sequential recurrence (register-direct; writes ybuf = vraw region)
    scan_kernel<<<BB * HH * 4, 64, 0, stream>>>(PK, rbuf, dbuf, vbuf, BC, ybuf);

    // 8) groupnorm + residual + gate (writes zbuf = dbuf region)
    gn_kernel<<<BB * TT * HH / 4, 256, 0, stream>>>(ybuf, rbuf, kbuf, vbuf, gbuf, ln_w, ln_b, r_k, zbuf);

    // 9) output projection -> d_out (f32)
    final_kernel<<<dim3(16, 8), 256, 0, stream>>>(zbuf, WoT, (float*)d_out);
}

// Round 8
// 608.581 us; speedup vs baseline: 1.0670x; 1.0670x over previous
//
#include <hip/hip_runtime.h>
#include <hip/hip_bf16.h>
#include <cstdint>
#include <cstddef>

typedef __hip_bfloat16 bf16;
typedef __bf16 bf16x8 __attribute__((ext_vector_type(8)));
typedef float f32x4 __attribute__((ext_vector_type(4)));

#define BB 2
#define TT 1024
#define CC 1024
#define HH 16
#define PKS 264   // floats per (bh,t) block: k[64] kk[64] bb[64] v[64] bt ct pad

__device__ __forceinline__ bf16 f2b(float v){ return __float2bfloat16(v); }

// quad (4-lane) sum via DPP quad_perm — VALU latency, no DS pipe
__device__ __forceinline__ float quad_add(float x) {
    x += __int_as_float(__builtin_amdgcn_mov_dpp(__float_as_int(x), 0xB1, 0xF, 0xF, true)); // xor 1
    x += __int_as_float(__builtin_amdgcn_mov_dpp(__float_as_int(x), 0x4E, 0xF, 0xF, true)); // xor 2
    return x;
}

// ---------------- batched transpose+convert: f32 [R][S] -> bf16 [S][R] ----------------
struct TrDesc { const float* in; bf16* out; int R, S; };
struct TrArgs { TrDesc d[12]; };

__global__ __launch_bounds__(256) void transpose_batch(TrArgs args)
{
    TrDesc t = args.d[blockIdx.z];
    __shared__ float tile[32][33];
    int s0 = blockIdx.x * 32, r0 = blockIdx.y * 32;
    if (s0 >= t.S || r0 >= t.R) return;      // block-uniform early exit
    int tx = threadIdx.x & 31, ty = threadIdx.x >> 5;
#pragma unroll
    for (int i = 0; i < 4; i++) {
        int r = r0 + ty + i * 8, s = s0 + tx;
        if (r < t.R && s < t.S) tile[ty + i * 8][tx] = t.in[(size_t)r * t.S + s];
    }
    __syncthreads();
#pragma unroll
    for (int i = 0; i < 4; i++) {
        int s = s0 + ty + i * 8, r = r0 + tx;
        if (s < t.S && r < t.R) t.out[(size_t)s * t.R + r] = f2b(tile[tx][ty + i * 8]);
    }
}

// ---------------- token-shift mix (f32 in -> bf16 out) + v_first passthrough ----------------
__global__ __launch_bounds__(256) void mix_kernel(
    const float* __restrict__ x, const float* __restrict__ vfirst,
    const float* __restrict__ mr, const float* __restrict__ mw, const float* __restrict__ mk,
    const float* __restrict__ mv, const float* __restrict__ ma, const float* __restrict__ mg,
    bf16* __restrict__ xr, bf16* __restrict__ xw, bf16* __restrict__ xk,
    bf16* __restrict__ xv, bf16* __restrict__ xa, bf16* __restrict__ xg,
    float* __restrict__ vout)
{
    int row = blockIdx.x;
    int t = row & (TT - 1);
    size_t base = (size_t)row * CC;
    for (int c = threadIdx.x; c < CC; c += 256) {
        float xc = x[base + c];
        float xp = (t > 0) ? x[base - CC + c] : 0.f;
        float d = xp - xc;
        xr[base + c] = f2b(xc + d * mr[c]);
        xw[base + c] = f2b(xc + d * mw[c]);
        xk[base + c] = f2b(xc + d * mk[c]);
        xv[base + c] = f2b(xc + d * mv[c]);
        xa[base + c] = f2b(xc + d * ma[c]);
        xg[base + c] = f2b(xc + d * mg[c]);
        vout[base + c] = vfirst[base + c];   // exact f32 passthrough
    }
}

// ---------------- shared MFMA tile body: 128x128 tile of A[M,K] @ BT[N,K]^T ----------------
template <class EmitF>
__device__ __forceinline__ void gemm_tile(const bf16* __restrict__ A, const bf16* __restrict__ BT,
                                          int K, int m0, int n0, EmitF emit)
{
    __shared__ __align__(16) bf16 Atile[128 * 32];
    __shared__ __align__(16) bf16 Btile[128 * 32];
    int tid = threadIdx.x;
    int w = tid >> 6, lane = tid & 63;
    int wr = w >> 1, wc = w & 1;
    int quad = lane >> 4, l16 = lane & 15;

    f32x4 zero = {0.f, 0.f, 0.f, 0.f};
    f32x4 acc[4][4];
#pragma unroll
    for (int i = 0; i < 4; i++)
#pragma unroll
        for (int j = 0; j < 4; j++) acc[i][j] = zero;

    int rr = lane >> 2;            // 0..15
    int cs = lane & 3;             // chunk slot in LDS
    int ra0 = w * 32 + rr;         // rows this lane stages
    int ra1 = ra0 + 16;
    int cg0 = cs ^ ((ra0 >> 1) & 3);   // global chunk (XOR swizzle)
    int cg1 = cs ^ ((ra1 >> 1) & 3);

    for (int k0 = 0; k0 < K; k0 += 32) {
        uint4 av0 = *reinterpret_cast<const uint4*>(A  + (size_t)(m0 + ra0) * K + k0 + cg0 * 8);
        uint4 av1 = *reinterpret_cast<const uint4*>(A  + (size_t)(m0 + ra1) * K + k0 + cg1 * 8);
        uint4 bv0 = *reinterpret_cast<const uint4*>(BT + (size_t)(n0 + ra0) * K + k0 + cg0 * 8);
        uint4 bv1 = *reinterpret_cast<const uint4*>(BT + (size_t)(n0 + ra1) * K + k0 + cg1 * 8);
        __syncthreads();           // previous tile's reads complete
        *reinterpret_cast<uint4*>(&Atile[ra0 * 32 + cs * 8]) = av0;
        *reinterpret_cast<uint4*>(&Atile[ra1 * 32 + cs * 8]) = av1;
        *reinterpret_cast<uint4*>(&Btile[ra0 * 32 + cs * 8]) = bv0;
        *reinterpret_cast<uint4*>(&Btile[ra1 * 32 + cs * 8]) = bv1;
        __syncthreads();           // staging visible

        bf16x8 af[4], bfr[4];
#pragma unroll
        for (int mi = 0; mi < 4; mi++) {
            int m = wr * 64 + mi * 16 + l16;
            int c2 = quad ^ ((m >> 1) & 3);
            af[mi] = *reinterpret_cast<const bf16x8*>(&Atile[m * 32 + c2 * 8]);
        }
#pragma unroll
        for (int ni = 0; ni < 4; ni++) {
            int n = wc * 64 + ni * 16 + l16;
            int c2 = quad ^ ((n >> 1) & 3);
            bfr[ni] = *reinterpret_cast<const bf16x8*>(&Btile[n * 32 + c2 * 8]);
        }
#pragma unroll
        for (int mi = 0; mi < 4; mi++)
#pragma unroll
            for (int ni = 0; ni < 4; ni++)
                acc[mi][ni] = __builtin_amdgcn_mfma_f32_16x16x32_bf16(af[mi], bfr[ni], acc[mi][ni], 0, 0, 0);
    }

#pragma unroll
    for (int mi = 0; mi < 4; mi++)
#pragma unroll
        for (int ni = 0; ni < 4; ni++)
#pragma unroll
            for (int rg = 0; rg < 4; rg++) {
                int m = m0 + wr * 64 + mi * 16 + quad * 4 + rg;
                int n = n0 + wc * 64 + ni * 16 + l16;
                emit(m, n, acc[mi][ni][rg]);
            }
}

// ---------------- big projections r/k/v: z-batched, N=K=1024, f32 out ----------------
struct B3Args { const bf16* A[3]; const bf16* BT[3]; float* out[3]; };
__global__ __launch_bounds__(256) void big3_kernel(B3Args args)
{
    int z = blockIdx.z;
    float* out = args.out[z];
    gemm_tile(args.A[z], args.BT[z], 1024, blockIdx.x * 128, blockIdx.y * 128,
              [&](int m, int n, float v) { out[(size_t)m * 1024 + n] = v; });
}

// ---------------- lora stage 1: z-batched (different A per z), small N, bf16 out ----------------
struct L1Desc { const bf16* A; const bf16* BT; bf16* outB; int N; int mode; }; // mode: 0 plain, 2 tanh, 3 sigmoid
struct L1Args { L1Desc d[4]; };
__global__ __launch_bounds__(256) void lora1_kernel(L1Args args)
{
    L1Desc dz = args.d[blockIdx.z];
    gemm_tile(dz.A, dz.BT, 1024, blockIdx.x * 128, 0,
              [&](int m, int n, float v) {
                  if (n < dz.N) {
                      float r = (dz.mode == 2) ? tanhf(v)
                              : (dz.mode == 3) ? 1.f / (1.f + expf(-v)) : v;
                      dz.outB[(size_t)m * dz.N + n] = f2b(r);
                  }
              });
}

// ---------------- lora stage 2 (+g2): z-batched, N=1024, f32 out, fused epilogues ----------------
struct L2Desc { const bf16* A; const bf16* BT; const float* bias; float* outF; int K; int mode; };
struct L2Args { L2Desc d[4]; const float* vraw; const float* vfirst; };
__global__ __launch_bounds__(256) void lora2_kernel(L2Args args)
{
    L2Desc dz = args.d[blockIdx.z];
    gemm_tile(dz.A, dz.BT, dz.K, blockIdx.x * 128, blockIdx.y * 128,
              [&](int m, int n, float v) {
                  size_t idx = (size_t)m * 1024 + n;
                  if (dz.mode == 4) {
                      float xx = v + dz.bias[n];
                      float ww = -log1pf(expf(-xx)) - 0.5f;   // -softplus(-x) - 0.5
                      dz.outF[idx] = expf(-expf(ww));
                  } else if (dz.mode == 5) {
                      float xx = v + dz.bias[n];
                      dz.outF[idx] = 1.f / (1.f + expf(-xx));
                  } else if (dz.mode == 6) {
                      float gate = 1.f / (1.f + expf(-(v + dz.bias[n])));
                      float vr = args.vraw[idx];
                      dz.outF[idx] = vr + (args.vfirst[idx] - vr) * gate;
                  } else {
                      dz.outF[idx] = v;
                  }
              });
}

// ---------------- final output projection ----------------
__global__ __launch_bounds__(256) void final_kernel(const bf16* __restrict__ A, const bf16* __restrict__ BT,
                                                    float* __restrict__ out)
{
    gemm_tile(A, BT, 1024, blockIdx.x * 128, blockIdx.y * 128,
              [&](int m, int n, float v) { out[(size_t)m * 1024 + n] = v; });
}

// ---------------- pack: kk norm, k scale -> contiguous PK block per (bh,t) ----------------
// PK[bh][t] block (264 floats): k[0..63], kk[64..127], bb[128..191], v[192..255], bt@256, ct@257
__global__ __launch_bounds__(256) void pack_kernel(
    float* __restrict__ k, const float* __restrict__ a, const float* __restrict__ r,
    const float* __restrict__ v,
    const float* __restrict__ kkw, const float* __restrict__ kaw,
    float* __restrict__ PK)
{
    int tid = threadIdx.x;
    int wave = tid >> 6, lane = tid & 63;
    int idx = blockIdx.x * 4 + wave;        // (b*TT+t)*HH + h
    size_t off = (size_t)idx * 64 + lane;
    int c = (idx & 15) * 64 + lane;
    float kraw = k[off];
    float av = a[off];
    float kkv = kraw * kkw[c];
    float s = kkv * kkv;
#pragma unroll
    for (int m = 32; m; m >>= 1) s += __shfl_xor(s, m);
    float kkn = kkv / fmaxf(sqrtf(s), 1e-12f);
    float ks = kraw * (1.f + (av - 1.f) * kaw[c]);
    k[off] = ks;                            // write-back for gn_kernel
    float bb = kkn * av;
    float rv = r[off];
    float bt = bb * rv, ct = ks * rv;
#pragma unroll
    for (int m = 32; m; m >>= 1) { bt += __shfl_xor(bt, m); ct += __shfl_xor(ct, m); }
    int b = idx >> 14;                      // / (TT*HH)
    int h = idx & 15;
    int t = (idx >> 4) & (TT - 1);
    size_t sidx = (size_t)(b * HH + h) * TT + t;
    float* pw = PK + sidx * PKS;
    pw[lane] = ks; pw[64 + lane] = kkn; pw[128 + lane] = bb; pw[192 + lane] = v[off];
    if (lane == 0) { pw[256] = bt; pw[257] = ct; }
}

// ---------------- sequential state recurrence (register-direct, depth-3 prefetch) ----------------
// 1 wave/block; wave owns rows [wq*16, wq*16+16). Lane (i=lane>>2, q=lane&3) owns S[row][16q..16q+16).
// All loads are immediate-offset off per-buffer base pointers (minimal addr VALU, nothing to sink).
struct Step {
    f32x4 q4[4], d4[4], r4[4], k4[4], b4[4];
    float vi; float2 bc;
};

__device__ __forceinline__ void load_step(Step& s, const float* __restrict__ pj,
                                          const float* __restrict__ pr, const float* __restrict__ pd,
                                          const float* __restrict__ pv, const float* __restrict__ pb)
{
    // order: earliest-needed first (kk heads the sa chain, then d/r for od, then k/bb/v/bc)
#pragma unroll
    for (int m = 0; m < 4; m++) s.q4[m] = *(const f32x4*)(pj + 64 + 4 * m);
#pragma unroll
    for (int m = 0; m < 4; m++) s.d4[m] = *(const f32x4*)(pd + 4 * m);
#pragma unroll
    for (int m = 0; m < 4; m++) s.r4[m] = *(const f32x4*)(pr + 4 * m);
#pragma unroll
    for (int m = 0; m < 4; m++) s.k4[m] = *(const f32x4*)(pj + 4 * m);
#pragma unroll
    for (int m = 0; m < 4; m++) s.b4[m] = *(const f32x4*)(pj + 128 + 4 * m);
    s.vi = *pv;
    s.bc = *(const float2*)pb;
}

__device__ __forceinline__ float step_update(const Step& sd, float S[16])
{
    float s0 = 0, s1 = 0, s2 = 0, s3 = 0;
    float o0 = 0, o1 = 0, o2 = 0, o3 = 0;
#pragma unroll
    for (int m = 0; m < 4; m++) {
        s0 = fmaf(S[4 * m + 0], sd.q4[m][0], s0);
        s1 = fmaf(S[4 * m + 1], sd.q4[m][1], s1);
        s2 = fmaf(S[4 * m + 2], sd.q4[m][2], s2);
        s3 = fmaf(S[4 * m + 3], sd.q4[m][3], s3);
        o0 = fmaf(S[4 * m + 0] * sd.d4[m][0], sd.r4[m][0], o0);
        o1 = fmaf(S[4 * m + 1] * sd.d4[m][1], sd.r4[m][1], o1);
        o2 = fmaf(S[4 * m + 2] * sd.d4[m][2], sd.r4[m][2], o2);
        o3 = fmaf(S[4 * m + 3] * sd.d4[m][3], sd.r4[m][3], o3);
    }
    float sa = -((s0 + s1) + (s2 + s3));
    sa = quad_add(sa);                    // full-row sa (all 4 lanes)
    float od = quad_add((o0 + o1) + (o2 + o3));
    float o = fmaf(sd.vi, sd.bc.y, fmaf(sa, sd.bc.x, od));
#pragma unroll
    for (int m = 0; m < 16; m++) {
        int mm = m >> 2, e = m & 3;
        S[m] = fmaf(sd.vi, sd.k4[mm][e], fmaf(sa, sd.b4[mm][e], S[m] * sd.d4[mm][e]));
    }
    return o;
}

__global__ __launch_bounds__(64, 1) void scan_kernel(
    const float* __restrict__ PK, const float* __restrict__ rbuf,
    const float* __restrict__ dbuf, float* __restrict__ ybuf)
{
    const int lane = threadIdx.x;
    const int bh = blockIdx.x >> 2;
    const int b = bh >> 4, h = bh & 15;
    const int wq = blockIdx.x & 3;
    const int row = wq * 16 + (lane >> 2);
    const int q = lane & 3, jb = q * 16;

    float S[16];
#pragma unroll
    for (int m = 0; m < 16; m++) S[m] = 0.f;

    const float* base = PK + (size_t)bh * TT * PKS;
    const float* pj = base + jb;                 // k/kk/bb/v slices (imm offsets)
    const float* pv = base + 192 + row;
    const float* pb = base + 256;
    size_t ebase = (size_t)b * TT * CC + h * 64 + jb;
    const float* prA = rbuf + ebase;             // per-buffer r/d pointers (stride CC > imm range)
    const float* prB = prA + CC;
    const float* prC = prB + CC;
    const float* pdA = dbuf + ebase;
    const float* pdB = pdA + CC;
    const float* pdC = pdB + CC;

    Step A, Bs, Cs;
    load_step(A,  pj,           prA, pdA, pv,           pb);
    load_step(Bs, pj + PKS,     prB, pdB, pv + PKS,     pb + PKS);
    load_step(Cs, pj + 2 * PKS, prC, pdC, pv + 2 * PKS, pb + 2 * PKS);
    pj += 3 * PKS; pv += 3 * PKS; pb += 3 * PKS;
    prA += 3 * CC; prB += 3 * CC; prC += 3 * CC;
    pdA += 3 * CC; pdB += 3 * CC; pdC += 3 * CC;

    float* py = ybuf + (size_t)b * TT * CC + h * 64 + row;

    for (int t = 0; t < 1023; t += 3) {
        float o = step_update(A, S);
        if (q == 0) *py = o;
        py += CC;
        load_step(A, pj, prA, pdA, pv, pb);                                    // t+3
        __builtin_amdgcn_sched_barrier(0);

        o = step_update(Bs, S);
        if (q == 0) *py = o;
        py += CC;
        load_step(Bs, pj + PKS, prB, pdB, pv + PKS, pb + PKS);                 // t+4 (tail OOB reads unused)
        __builtin_amdgcn_sched_barrier(0);

        o = step_update(Cs, S);
        if (q == 0) *py = o;
        py += CC;
        load_step(Cs, pj + 2 * PKS, prC, pdC, pv + 2 * PKS, pb + 2 * PKS);     // t+5
        __builtin_amdgcn_sched_barrier(0);

        pj += 3 * PKS; pv += 3 * PKS; pb += 3 * PKS;
        prA += 3 * CC; prB += 3 * CC; prC += 3 * CC;
        pdA += 3 * CC; pdB += 3 * CC; pdC += 3 * CC;
    }
    // tail t = 1023 (A holds it)
    float o = step_update(A, S);
    if (q == 0) *py = o;
}

// ---------------- groupnorm + residual + gate -> z (bf16), 4 heads/block ----------------
__global__ __launch_bounds__(256) void gn_kernel(
    const float* __restrict__ y, const float* __restrict__ r, const float* __restrict__ k,
    const float* __restrict__ v, const float* __restrict__ g,
    const float* __restrict__ lnw, const float* __restrict__ lnb,
    const float* __restrict__ rk, bf16* __restrict__ z)
{
    int tid = threadIdx.x;
    int idx = blockIdx.x * 4 + (tid >> 6);   // (b*T+t)*16 + h
    int lane = tid & 63;
    size_t off = (size_t)idx * 64 + lane;
    int c = (idx & 15) * 64 + lane;
    float yv = y[off];
    float rv = r[off], kv = k[off], vv = v[off];
    float s1 = yv, s2 = yv * yv, s3 = rv * kv * rk[c];
#pragma unroll
    for (int m = 32; m; m >>= 1) {
        s1 += __shfl_xor(s1, m);
        s2 += __shfl_xor(s2, m);
        s3 += __shfl_xor(s3, m);
    }
    float mu = s1 * (1.f / 64.f);
    float var = fmaxf(s2 * (1.f / 64.f) - mu * mu, 0.f);
    float yn = (yv - mu) * rsqrtf(var + 64e-5f) * lnw[c] + lnb[c];
    float out = (yn + s3 * vv) * g[off];
    z[off] = f2b(out);
}

// ---------------- host ----------------
extern "C" void kernel_launch(void* const* d_in, const int* in_sizes, int n_in,
                              void* d_out, int out_size, void* d_ws, size_t ws_size,
                              hipStream_t stream)
{
    const float* x       = (const float*)d_in[0];
    const float* v_first = (const float*)d_in[1];
    const float* x_r = (const float*)d_in[2];
    const float* x_w = (const float*)d_in[3];
    const float* x_k = (const float*)d_in[4];
    const float* x_v = (const float*)d_in[5];
    const float* x_a = (const float*)d_in[6];
    const float* x_g = (const float*)d_in[7];
    const float* w1 = (const float*)d_in[8];
    const float* w2 = (const float*)d_in[9];
    const float* w0 = (const float*)d_in[10];
    const float* a1 = (const float*)d_in[11];
    const float* a2 = (const float*)d_in[12];
    const float* a0 = (const float*)d_in[13];
    const float* v1 = (const float*)d_in[14];
    const float* v2 = (const float*)d_in[15];
    const float* v0 = (const float*)d_in[16];
    const float* g1 = (const float*)d_in[17];
    const float* g2 = (const float*)d_in[18];
    const float* k_k = (const float*)d_in[19];
    const float* k_a = (const float*)d_in[20];
    const float* r_k = (const float*)d_in[21];
    const float* W_r = (const float*)d_in[22];
    const float* W_k = (const float*)d_in[23];
    const float* W_v = (const float*)d_in[24];
    const float* W_o = (const float*)d_in[25];
    const float* ln_w = (const float*)d_in[26];
    const float* ln_b = (const float*)d_in[27];

    const size_t BTC = (size_t)BB * TT * CC;   // 2M
    const int M = BB * TT;                     // 2048

    char* ws = (char*)d_ws;
    size_t off = 0;
    auto alloc = [&](size_t bytes) -> char* {
        char* p = ws + off;
        off += (bytes + 255) & ~(size_t)255;
        return p;
    };

    // ---- region0: everything here is dead before pack_kernel; PK aliases it ----
    bf16* xr = (bf16*)alloc(BTC * 2);
    bf16* xw = (bf16*)alloc(BTC * 2);
    bf16* xk = (bf16*)alloc(BTC * 2);
    bf16* xv = (bf16*)alloc(BTC * 2);
    bf16* xa = (bf16*)alloc(BTC * 2);
    bf16* xg = (bf16*)alloc(BTC * 2);
    bf16* WrT = (bf16*)alloc(1024 * 1024 * 2);
    bf16* WkT = (bf16*)alloc(1024 * 1024 * 2);
    bf16* WvT = (bf16*)alloc(1024 * 1024 * 2);
    bf16* w1T = (bf16*)alloc(128 * 1024 * 2);   // 64 rows used, pad benign
    bf16* a1T = (bf16*)alloc(128 * 1024 * 2);
    bf16* v1T = (bf16*)alloc(128 * 1024 * 2);   // 32 rows used
    bf16* g1T = (bf16*)alloc(128 * 1024 * 2);
    bf16* w2T = (bf16*)alloc(1024 * 64 * 2);
    bf16* a2T = (bf16*)alloc(1024 * 64 * 2);
    bf16* v2T = (bf16*)alloc(1024 * 32 * 2);
    bf16* g2T = (bf16*)alloc(1024 * 128 * 2);
    bf16* h_w = (bf16*)alloc((size_t)M * 64 * 2);
    bf16* h_a = (bf16*)alloc((size_t)M * 64 * 2);
    bf16* h_v = (bf16*)alloc((size_t)M * 32 * 2);
    bf16* h_g = (bf16*)alloc((size_t)M * 128 * 2);

    // PK aliases region0 (~34.6 MB); continue past max(region0, PK)
    float* PK = (float*)ws;
    size_t pk_end = (size_t)BB * HH * TT * PKS * 4;   // 34,603,008
    if (off < pk_end) off = pk_end;
    off = (off + 255) & ~(size_t)255;

    // ---- live across pack/scan ----
    bf16* WoT = (bf16*)alloc(1024 * 1024 * 2);
    float* rbuf = (float*)alloc(BTC * 4);
    float* kbuf = (float*)alloc(BTC * 4);
    float* vraw = (float*)alloc(BTC * 4);   // reused as ybuf after lora2
    float* vbuf = (float*)alloc(BTC * 4);
    float* dbuf = (float*)alloc(BTC * 4);   // reused as zbuf (bf16) after scan
    float* abuf = (float*)alloc(BTC * 4);
    float* gbuf = (float*)alloc(BTC * 4);

    float* ybuf = vraw;
    bf16*  zbuf = (bf16*)dbuf;

    (void)in_sizes; (void)n_in; (void)out_size; (void)ws_size;

    // 1) all weight transposes in one launch
    TrArgs ta;
    ta.d[0]  = {W_r, WrT, 1024, 1024};
    ta.d[1]  = {W_k, WkT, 1024, 1024};
    ta.d[2]  = {W_v, WvT, 1024, 1024};
    ta.d[3]  = {W_o, WoT, 1024, 1024};
    ta.d[4]  = {w1, w1T, 1024, 64};
    ta.d[5]  = {a1, a1T, 1024, 64};
    ta.d[6]  = {v1, v1T, 1024, 32};
    ta.d[7]  = {g1, g1T, 1024, 128};
    ta.d[8]  = {w2, w2T, 64, 1024};
    ta.d[9]  = {a2, a2T, 64, 1024};
    ta.d[10] = {v2, v2T, 32, 1024};
    ta.d[11] = {g2, g2T, 128, 1024};
    transpose_batch<<<dim3(32, 32, 12), 256, 0, stream>>>(ta);

    // 2) token-shift mix (+ v_first passthrough)
    float* vout = (float*)d_out + BTC;
    mix_kernel<<<BB * TT, 256, 0, stream>>>(x, v_first, x_r, x_w, x_k, x_v, x_a, x_g,
                                            xr, xw, xk, xv, xa, xg, vout);

    // 3) big projections r/k/v
    B3Args b3;
    b3.A[0] = xr; b3.A[1] = xk; b3.A[2] = xv;
    b3.BT[0] = WrT; b3.BT[1] = WkT; b3.BT[2] = WvT;
    b3.out[0] = rbuf; b3.out[1] = kbuf; b3.out[2] = vraw;
    big3_kernel<<<dim3(16, 8, 3), 256, 0, stream>>>(b3);

    // 4) lora stage 1
    L1Args l1;
    l1.d[0] = {xw, w1T, h_w, 64, 2};
    l1.d[1] = {xa, a1T, h_a, 64, 0};
    l1.d[2] = {xv, v1T, h_v, 32, 0};
    l1.d[3] = {xg, g1T, h_g, 128, 3};
    lora1_kernel<<<dim3(16, 1, 4), 256, 0, stream>>>(l1);

    // 5) lora stage 2 + g2
    L2Args l2;
    l2.d[0] = {h_w, w2T, w0, dbuf, 64, 4};
    l2.d[1] = {h_a, a2T, a0, abuf, 64, 5};
    l2.d[2] = {h_v, v2T, v0, vbuf, 32, 6};
    l2.d[3] = {h_g, g2T, nullptr, gbuf, 128, 0};
    l2.vraw = vraw; l2.vfirst = v_first;
    lora2_kernel<<<dim3(16, 8, 4), 256, 0, stream>>>(l2);

    // 6) pack (contiguous PK blocks incl. bt/ct; writes scaled k back to kbuf)
    pack_kernel<<<BB * TT * HH / 4, 256, 0, stream>>>(kbuf, abuf, rbuf, vbuf, k_k, k_a, PK);

    // 7) sequential recurrence (register-direct, depth-3; writes ybuf = vraw region)
    scan_kernel<<<BB * HH * 4, 64, 0, stream>>>(PK, rbuf, dbuf, ybuf);

    // 8) groupnorm + residual + gate (writes zbuf = dbuf region)
    gn_kernel<<<BB * TT * HH / 4, 256, 0, stream>>>(ybuf, rbuf, kbuf, vbuf, gbuf, ln_w, ln_b, r_k, zbuf);

    // 9) output projection -> d_out (f32)
    final_kernel<<<dim3(16, 8), 256, 0, stream>>>(zbuf, WoT, (float*)d_out);
}